// Round 8
// baseline (176.550 us; speedup 1.0000x reference)
//
#include <hip/hip_runtime.h>

// GCN 2-layer encoder for MI355X (gfx950) — round 8.
// r7 post-mortem: fill-block count (512->1024) and 4-wide ILP changed nothing
// -> the fp32 VALU GEMM1 (not the fill) runs the full 46us of gemm_fill
// (VALUBusy 27% == 1.64GF/46us/157TF). r8: both GEMMs moved to MFMA bf16 with
// split-precision inputs (x=xh+xl, W=wh+wl; acc = xh*wh + xl*wh + xh*wl in
// f32 accumulators) == fp32 accuracy at matrix-core rates. Fill blocks first
// in grid (long pole starts earliest).
//
// Pipeline (8 dispatches):
//   k_init -> k_count -> k_scan1 -> k_scan3 -> k_fill_gemm1(fill || mfma-gemm1)
//   -> k_gather_relu(h1b -> aggb bf16) -> k_gemm2_mfma(aggb -> h2b)
//   -> k_gather<64>(h2b -> out f32)

constexpr int IN_CH  = 128;
constexpr int HID    = 128;
constexpr int OUT_CH = 64;
constexpr int SCAN_CHUNK = 4096;

using short8v = __attribute__((ext_vector_type(8))) short;
using f32x4v  = __attribute__((ext_vector_type(4))) float;

__device__ __forceinline__ unsigned short f2bf_rne(float f) {
    unsigned int u = __float_as_uint(f);
    u += 0x7FFFu + ((u >> 16) & 1u);
    return (unsigned short)(u >> 16);
}
__device__ __forceinline__ float bf2f(unsigned short h) {
    return __uint_as_float((unsigned int)h << 16);
}

__device__ __forceinline__ bool probe_is64(const int* __restrict__ ei) {
    const int v = ei[2 * (threadIdx.x & 63) + 1];
    return __ballot(v != 0) == 0ull;
}

__device__ __forceinline__ void load_idx4(const int* __restrict__ ei, bool is64,
                                          long long base, int e0, int n,
                                          bool al64, bool al32, int* out) {
    if (is64) {
        if (n == 4 && al64) {
            const int4 a = *reinterpret_cast<const int4*>(ei + 2 * (base + e0));
            const int4 b = *reinterpret_cast<const int4*>(ei + 2 * (base + e0) + 4);
            out[0] = a.x; out[1] = a.z; out[2] = b.x; out[3] = b.z;
        } else {
            for (int j = 0; j < n; ++j) out[j] = ei[2 * (base + e0 + j)];
        }
    } else {
        if (n == 4 && al32) {
            const int4 a = *reinterpret_cast<const int4*>(ei + base + e0);
            out[0] = a.x; out[1] = a.y; out[2] = a.z; out[3] = a.w;
        } else {
            for (int j = 0; j < n; ++j) out[j] = ei[base + e0 + j];
        }
    }
}

__global__ void k_init(int* __restrict__ indeg, int N) {
    const int i = blockIdx.x * blockDim.x + threadIdx.x;
    const int n4 = N / 4;
    for (int j = i; j < n4; j += gridDim.x * blockDim.x)
        reinterpret_cast<int4*>(indeg)[j] = make_int4(0, 0, 0, 0);
    const int tail = n4 * 4 + i;
    if (tail < N) indeg[tail] = 0;
}

__global__ void k_count(const int* __restrict__ ei, int* __restrict__ indeg, int E) {
    const bool is64 = probe_is64(ei);
    const bool al64 = (E % 2) == 0;
    const bool al32 = (E % 4) == 0;
    const int idx    = blockIdx.x * blockDim.x + threadIdx.x;
    const int stride = gridDim.x * blockDim.x;
    for (int e0 = idx * 4; e0 < E; e0 += stride * 4) {
        const int n = min(4, E - e0);
        int d[4];
        load_idx4(ei, is64, (long long)E, e0, n, al64, al32, d);
        for (int j = 0; j < n; ++j) atomicAdd(&indeg[d[j]], 1);
    }
}

__global__ __launch_bounds__(256) void k_scan1(const int* __restrict__ indeg,
                                               int* __restrict__ row_ptr,
                                               float* __restrict__ dinv,
                                               int* __restrict__ partials, int N) {
    const int t    = threadIdx.x;
    const int base = blockIdx.x * SCAN_CHUNK + t * 16;
    int v[16];
    if (base + 15 < N) {
        const int4* p = reinterpret_cast<const int4*>(indeg + base);
#pragma unroll
        for (int q = 0; q < 4; ++q) {
            const int4 a = p[q];
            v[q * 4 + 0] = a.x; v[q * 4 + 1] = a.y;
            v[q * 4 + 2] = a.z; v[q * 4 + 3] = a.w;
        }
    } else {
#pragma unroll
        for (int j = 0; j < 16; ++j)
            v[j] = (base + j < N) ? indeg[base + j] : 0;
    }
#pragma unroll
    for (int j = 0; j < 16; ++j)
        if (base + j < N) dinv[base + j] = rsqrtf((float)(v[j] + 1));

    int sum = 0;
#pragma unroll
    for (int j = 0; j < 16; ++j) { const int tv = v[j]; v[j] = sum; sum += tv; }

    int incl = sum;
#pragma unroll
    for (int off = 1; off < 64; off <<= 1) {
        int tt = __shfl_up(incl, off, 64);
        if ((t & 63) >= off) incl += tt;
    }
    __shared__ int wsum[4];
    if ((t & 63) == 63) wsum[t >> 6] = incl;
    __syncthreads();
    int woff = 0;
#pragma unroll
    for (int w = 0; w < 4; ++w) woff += (w < (t >> 6)) ? wsum[w] : 0;
    const int texcl = woff + incl - sum;

#pragma unroll
    for (int j = 0; j < 16; ++j)
        if (base + j < N) row_ptr[base + j] = texcl + v[j];
    if (t == 255) partials[blockIdx.x] = woff + incl;
}

__global__ __launch_bounds__(256) void k_scan3(const int* __restrict__ partials,
                                               int* __restrict__ row_ptr,
                                               int* __restrict__ cursor,
                                               int N, int nblk) {
    int off = 0;
    for (int w = 0; w < (int)blockIdx.x; ++w) off += partials[w];

    const int base = blockIdx.x * SCAN_CHUNK + threadIdx.x * 16;
    if (base + 15 < N) {
        int4* rp = reinterpret_cast<int4*>(row_ptr + base);
        int4* cp = reinterpret_cast<int4*>(cursor + base);
#pragma unroll
        for (int q = 0; q < 4; ++q) {
            int4 a = rp[q];
            a.x += off; a.y += off; a.z += off; a.w += off;
            rp[q] = a; cp[q] = a;
        }
    } else {
#pragma unroll
        for (int j = 0; j < 16; ++j) {
            const int i = base + j;
            if (i < N) { const int r = row_ptr[i] + off; row_ptr[i] = r; cursor[i] = r; }
        }
    }
    if ((int)blockIdx.x == nblk - 1 && threadIdx.x == 255)
        row_ptr[N] = off + partials[nblk - 1];
}

// MFMA GEMM1: h1b[M x 128](bf16) = x[M x 128](f32) @ W1[128 x 128](f32).
// Split precision: x = xh+xl, W = wh+wl (bf16), acc += xh*wh + xl*wh + xh*wl.
// 4 waves, wave w owns 16 rows; A-frags global-direct; W staged transposed
// (wsT[n][k], stride 40) so B-frags are single b128 reads. 20.5 KB LDS.
__device__ __forceinline__ void gemm1_mfma(const float* __restrict__ X,
                                           const float* __restrict__ W,
                                           unsigned short* __restrict__ Y,
                                           int M, int blk) {
    constexpr int KSTR = 40;  // bf16 elems per wsT row (80 B, 16B-mult, bank-spread)
    __shared__ __align__(16) unsigned short wsTh[128 * KSTR];
    __shared__ __align__(16) unsigned short wsTl[128 * KSTR];

    const int tid = threadIdx.x;
    const int wv  = tid >> 6;
    const int ln  = tid & 63;
    const int m16 = ln & 15;
    const int g   = ln >> 4;
    const int arow = blk * 64 + wv * 16 + m16;   // A-operand row for this lane

    f32x4v acc[8];
#pragma unroll
    for (int n = 0; n < 8; ++n) acc[n] = {0.f, 0.f, 0.f, 0.f};

    for (int k0 = 0; k0 < 128; k0 += 32) {
        __syncthreads();
        // stage W chunk, transposed + split (32 k x 128 n)
#pragma unroll
        for (int q = 0; q < 4; ++q) {
            const int i  = tid + q * 256;     // float4 index, 0..1023
            const int k  = i >> 5;            // 0..31
            const int n4 = i & 31;
            const float4 v = *reinterpret_cast<const float4*>(
                W + (size_t)(k0 + k) * 128 + n4 * 4);
            const float f[4] = {v.x, v.y, v.z, v.w};
#pragma unroll
            for (int e = 0; e < 4; ++e) {
                const unsigned short h = f2bf_rne(f[e]);
                wsTh[(n4 * 4 + e) * KSTR + k] = h;
                wsTl[(n4 * 4 + e) * KSTR + k] = f2bf_rne(f[e] - bf2f(h));
            }
        }
        __syncthreads();

        // A fragments (8 f32 -> bf16 hi/lo)
        short8v ah, al;
        if (arow < M) {
            const float4 a0 = *reinterpret_cast<const float4*>(
                X + (size_t)arow * 128 + k0 + g * 8);
            const float4 a1 = *reinterpret_cast<const float4*>(
                X + (size_t)arow * 128 + k0 + g * 8 + 4);
            const float f[8] = {a0.x, a0.y, a0.z, a0.w, a1.x, a1.y, a1.z, a1.w};
#pragma unroll
            for (int e = 0; e < 8; ++e) {
                const unsigned short h = f2bf_rne(f[e]);
                ah[e] = (short)h;
                al[e] = (short)f2bf_rne(f[e] - bf2f(h));
            }
        } else {
#pragma unroll
            for (int e = 0; e < 8; ++e) { ah[e] = 0; al[e] = 0; }
        }

#pragma unroll
        for (int n = 0; n < 8; ++n) {
            const short8v bh = *reinterpret_cast<const short8v*>(
                &wsTh[(n * 16 + m16) * KSTR + g * 8]);
            const short8v bl = *reinterpret_cast<const short8v*>(
                &wsTl[(n * 16 + m16) * KSTR + g * 8]);
            acc[n] = __builtin_amdgcn_mfma_f32_16x16x32_bf16(ah, bh, acc[n], 0, 0, 0);
            acc[n] = __builtin_amdgcn_mfma_f32_16x16x32_bf16(al, bh, acc[n], 0, 0, 0);
            acc[n] = __builtin_amdgcn_mfma_f32_16x16x32_bf16(ah, bl, acc[n], 0, 0, 0);
        }
    }

    // D layout: row = g*4 + r, col = m16 (within 16x16 tile)
#pragma unroll
    for (int r = 0; r < 4; ++r) {
        const int orow = blk * 64 + wv * 16 + g * 4 + r;
        if (orow < M) {
#pragma unroll
            for (int n = 0; n < 8; ++n)
                Y[(size_t)orow * 128 + n * 16 + m16] = f2bf_rne(acc[n][r]);
        }
    }
}

// Dual-role dispatch; fill blocks FIRST (long pole starts earliest).
__global__ __launch_bounds__(256) void k_fill_gemm1(
    const float* __restrict__ X, const float* __restrict__ W,
    unsigned short* __restrict__ Y, int M, int fillBlocks,
    const int* __restrict__ ei, const float* __restrict__ dinv,
    int* __restrict__ cursor, int2* __restrict__ csr, int E) {
    if ((int)blockIdx.x >= fillBlocks) {
        gemm1_mfma(X, W, Y, M, blockIdx.x - fillBlocks);
    } else {
        const bool is64 = probe_is64(ei);
        const bool al64 = (E % 2) == 0;
        const bool al32 = (E % 4) == 0;
        const int nthr = fillBlocks * 256;
        const int idx  = blockIdx.x * 256 + threadIdx.x;
        for (int e0 = idx * 4; e0 < E; e0 += nthr * 4) {
            const int n = min(4, E - e0);
            int s[4], d[4];
            load_idx4(ei, is64, 0,            e0, n, true, true, s);
            load_idx4(ei, is64, (long long)E, e0, n, al64, al32, d);
            float w[4];
            for (int j = 0; j < n; ++j) w[j] = dinv[s[j]];
            int pos[4];
            for (int j = 0; j < n; ++j) pos[j] = atomicAdd(&cursor[d[j]], 1);
            for (int j = 0; j < n; ++j) {
                const unsigned long long rec =
                    (unsigned long long)(unsigned int)s[j] |
                    ((unsigned long long)__float_as_uint(w[j]) << 32);
                __builtin_nontemporal_store(
                    rec, reinterpret_cast<unsigned long long*>(csr) + pos[j]);
            }
        }
    }
}

// MFMA GEMM2: h2b[M x 64](bf16) = aggb[M x 128](bf16, exact) @ W2[128 x 64](f32).
// A is already bf16 (exact) -> only W2 split: acc += a*wh + a*wl.
__global__ __launch_bounds__(256) void k_gemm2_mfma(
    const unsigned short* __restrict__ Xb, const float* __restrict__ W,
    unsigned short* __restrict__ Y, int M) {
    constexpr int KSTR = 40;
    __shared__ __align__(16) unsigned short wsTh[64 * KSTR];
    __shared__ __align__(16) unsigned short wsTl[64 * KSTR];

    const int tid = threadIdx.x;
    const int wv  = tid >> 6;
    const int ln  = tid & 63;
    const int m16 = ln & 15;
    const int g   = ln >> 4;
    const int blk = blockIdx.x;
    const int arow = blk * 64 + wv * 16 + m16;

    f32x4v acc[4];
#pragma unroll
    for (int n = 0; n < 4; ++n) acc[n] = {0.f, 0.f, 0.f, 0.f};

    for (int k0 = 0; k0 < 128; k0 += 32) {
        __syncthreads();
        // stage W2 chunk (32 k x 64 n), transposed + split: 512 float4s
#pragma unroll
        for (int q = 0; q < 2; ++q) {
            const int i  = tid + q * 256;   // 0..511
            const int k  = i >> 4;          // 0..31
            const int n4 = i & 15;
            const float4 v = *reinterpret_cast<const float4*>(
                W + (size_t)(k0 + k) * 64 + n4 * 4);
            const float f[4] = {v.x, v.y, v.z, v.w};
#pragma unroll
            for (int e = 0; e < 4; ++e) {
                const unsigned short h = f2bf_rne(f[e]);
                wsTh[(n4 * 4 + e) * KSTR + k] = h;
                wsTl[(n4 * 4 + e) * KSTR + k] = f2bf_rne(f[e] - bf2f(h));
            }
        }
        __syncthreads();

        short8v a;
        if (arow < M) {
            a = *reinterpret_cast<const short8v*>(
                Xb + (size_t)arow * 128 + k0 + g * 8);
        } else {
#pragma unroll
            for (int e = 0; e < 8; ++e) a[e] = 0;
        }

#pragma unroll
        for (int n = 0; n < 4; ++n) {
            const short8v bh = *reinterpret_cast<const short8v*>(
                &wsTh[(n * 16 + m16) * KSTR + g * 8]);
            const short8v bl = *reinterpret_cast<const short8v*>(
                &wsTl[(n * 16 + m16) * KSTR + g * 8]);
            acc[n] = __builtin_amdgcn_mfma_f32_16x16x32_bf16(a, bh, acc[n], 0, 0, 0);
            acc[n] = __builtin_amdgcn_mfma_f32_16x16x32_bf16(a, bl, acc[n], 0, 0, 0);
        }
    }

#pragma unroll
    for (int r = 0; r < 4; ++r) {
        const int orow = blk * 64 + wv * 16 + g * 4 + r;
        if (orow < M) {
#pragma unroll
            for (int n = 0; n < 4; ++n)
                Y[(size_t)orow * 64 + n * 16 + m16] = f2bf_rne(acc[n][r]);
        }
    }
}

// aggb[n](bf16) = relu(b1 + h[n]*dinv[n]^2 + sum_e h[rec.src]*rec.w*dinv[n])
__global__ __launch_bounds__(256) void k_gather_relu(
    const unsigned short* __restrict__ h, const int* __restrict__ row_ptr,
    const int2* __restrict__ csr, const float* __restrict__ dinv,
    const float* __restrict__ b, unsigned short* __restrict__ aggb, int N) {
    constexpr int LPN = HID / 4;   // 32
    const int tid  = blockIdx.x * blockDim.x + threadIdx.x;
    const int node = tid / LPN;
    const int lane = tid % LPN;
    if (node >= N) return;

    const float dn = dinv[node];
    float4 acc = reinterpret_cast<const float4*>(b)[lane];
    {
        const float w = dn * dn;
        const ushort4 v = *reinterpret_cast<const ushort4*>(h + (size_t)node * HID + lane * 4);
        acc.x = fmaf(bf2f(v.x), w, acc.x); acc.y = fmaf(bf2f(v.y), w, acc.y);
        acc.z = fmaf(bf2f(v.z), w, acc.z); acc.w = fmaf(bf2f(v.w), w, acc.w);
    }

    const int e1 = row_ptr[node + 1];
    int e = row_ptr[node];
    for (; e + 1 < e1; e += 2) {
        const int2 r0 = csr[e];
        const int2 r1 = csr[e + 1];
        const float w0 = __int_as_float(r0.y) * dn;
        const float w1 = __int_as_float(r1.y) * dn;
        const ushort4 v0 = *reinterpret_cast<const ushort4*>(h + (size_t)r0.x * HID + lane * 4);
        const ushort4 v1 = *reinterpret_cast<const ushort4*>(h + (size_t)r1.x * HID + lane * 4);
        acc.x = fmaf(bf2f(v0.x), w0, acc.x); acc.y = fmaf(bf2f(v0.y), w0, acc.y);
        acc.z = fmaf(bf2f(v0.z), w0, acc.z); acc.w = fmaf(bf2f(v0.w), w0, acc.w);
        acc.x = fmaf(bf2f(v1.x), w1, acc.x); acc.y = fmaf(bf2f(v1.y), w1, acc.y);
        acc.z = fmaf(bf2f(v1.z), w1, acc.z); acc.w = fmaf(bf2f(v1.w), w1, acc.w);
    }
    if (e < e1) {
        const int2 r0 = csr[e];
        const float w0 = __int_as_float(r0.y) * dn;
        const ushort4 v0 = *reinterpret_cast<const ushort4*>(h + (size_t)r0.x * HID + lane * 4);
        acc.x = fmaf(bf2f(v0.x), w0, acc.x); acc.y = fmaf(bf2f(v0.y), w0, acc.y);
        acc.z = fmaf(bf2f(v0.z), w0, acc.z); acc.w = fmaf(bf2f(v0.w), w0, acc.w);
    }

    ushort4 o;
    o.x = f2bf_rne(fmaxf(acc.x, 0.f));
    o.y = f2bf_rne(fmaxf(acc.y, 0.f));
    o.z = f2bf_rne(fmaxf(acc.z, 0.f));
    o.w = f2bf_rne(fmaxf(acc.w, 0.f));
    *reinterpret_cast<ushort4*>(aggb + (size_t)node * HID + lane * 4) = o;
}

// out[n](f32) = b + h[n]*dinv[n]^2 + sum_e h[rec.src]*rec.w*dinv[n]
template <int C>
__global__ __launch_bounds__(256) void k_gather(const unsigned short* __restrict__ h,
                                                const int* __restrict__ row_ptr,
                                                const int2* __restrict__ csr,
                                                const float* __restrict__ dinv,
                                                const float* __restrict__ b,
                                                float* __restrict__ out, int N) {
    constexpr int LPN = C / 4;
    const int tid  = blockIdx.x * blockDim.x + threadIdx.x;
    const int node = tid / LPN;
    const int lane = tid % LPN;
    if (node >= N) return;

    const float dn = dinv[node];
    float4 acc = reinterpret_cast<const float4*>(b)[lane];
    {
        const float w = dn * dn;
        const ushort4 v = *reinterpret_cast<const ushort4*>(h + (size_t)node * C + lane * 4);
        acc.x = fmaf(bf2f(v.x), w, acc.x); acc.y = fmaf(bf2f(v.y), w, acc.y);
        acc.z = fmaf(bf2f(v.z), w, acc.z); acc.w = fmaf(bf2f(v.w), w, acc.w);
    }

    const int e1 = row_ptr[node + 1];
    int e = row_ptr[node];
    for (; e + 1 < e1; e += 2) {
        const int2 r0 = csr[e];
        const int2 r1 = csr[e + 1];
        const float w0 = __int_as_float(r0.y) * dn;
        const float w1 = __int_as_float(r1.y) * dn;
        const ushort4 v0 = *reinterpret_cast<const ushort4*>(h + (size_t)r0.x * C + lane * 4);
        const ushort4 v1 = *reinterpret_cast<const ushort4*>(h + (size_t)r1.x * C + lane * 4);
        acc.x = fmaf(bf2f(v0.x), w0, acc.x); acc.y = fmaf(bf2f(v0.y), w0, acc.y);
        acc.z = fmaf(bf2f(v0.z), w0, acc.z); acc.w = fmaf(bf2f(v0.w), w0, acc.w);
        acc.x = fmaf(bf2f(v1.x), w1, acc.x); acc.y = fmaf(bf2f(v1.y), w1, acc.y);
        acc.z = fmaf(bf2f(v1.z), w1, acc.z); acc.w = fmaf(bf2f(v1.w), w1, acc.w);
    }
    if (e < e1) {
        const int2 r0 = csr[e];
        const float w0 = __int_as_float(r0.y) * dn;
        const ushort4 v0 = *reinterpret_cast<const ushort4*>(h + (size_t)r0.x * C + lane * 4);
        acc.x = fmaf(bf2f(v0.x), w0, acc.x); acc.y = fmaf(bf2f(v0.y), w0, acc.y);
        acc.z = fmaf(bf2f(v0.z), w0, acc.z); acc.w = fmaf(bf2f(v0.w), w0, acc.w);
    }

    reinterpret_cast<float4*>(out + (size_t)node * C)[lane] = acc;
}

extern "C" void kernel_launch(void* const* d_in, const int* in_sizes, int n_in,
                              void* d_out, int out_size, void* d_ws, size_t ws_size,
                              hipStream_t stream) {
    const float* x  = (const float*)d_in[0];
    const int*   ei = (const int*)d_in[1];
    const float* W1 = (const float*)d_in[2];
    const float* b1 = (const float*)d_in[3];
    const float* W2 = (const float*)d_in[4];
    const float* b2 = (const float*)d_in[5];
    float* out = (float*)d_out;

    const int N = in_sizes[0] / IN_CH;   // 50000
    const int E = in_sizes[1] / 2;       // 600000
    const int NBLK = (N + SCAN_CHUNK - 1) / SCAN_CHUNK;   // 13

    char* wsb = (char*)d_ws;
    size_t off = 0;
    auto alloc = [&](size_t bytes) -> void* {
        void* p = wsb + off;
        off += (bytes + 255) & ~(size_t)255;
        return p;
    };
    int*   indeg    = (int*)alloc((size_t)N * sizeof(int));
    int*   partials = (int*)alloc(64 * sizeof(int));
    float* dinv     = (float*)alloc((size_t)N * sizeof(float));
    int*   row_ptr  = (int*)alloc(((size_t)N + 1) * sizeof(int));
    int2*  csr      = (int2*)alloc((size_t)E * sizeof(int2));
    unsigned short* h1b  = (unsigned short*)alloc((size_t)N * HID * sizeof(unsigned short));
    unsigned short* aggb = (unsigned short*)alloc((size_t)N * HID * sizeof(unsigned short));
    unsigned short* h2b  = (unsigned short*)alloc((size_t)N * OUT_CH * sizeof(unsigned short));
    int*   cursor   = indeg;   // indeg dead after k_scan1

    auto gs = [](long long n) { return (int)((n + 255) / 256); };

    k_init<<<64, 256, 0, stream>>>(indeg, N);
    k_count<<<gs((E + 3) / 4), 256, 0, stream>>>(ei, indeg, E);
    k_scan1<<<NBLK, 256, 0, stream>>>(indeg, row_ptr, dinv, partials, N);
    k_scan3<<<NBLK, 256, 0, stream>>>(partials, row_ptr, cursor, N, NBLK);

    // fill (first, long pole) || MFMA gemm1
    const int fillBlocks = 1024;
    const int gemmBlocks = (N + 63) / 64;   // 782
    k_fill_gemm1<<<fillBlocks + gemmBlocks, 256, 0, stream>>>(
        x, W1, h1b, N, fillBlocks, ei, dinv, cursor, csr, E);

    // gather1 + bias + ReLU -> bf16 agg
    k_gather_relu<<<gs((long long)N * (HID / 4)), 256, 0, stream>>>(
        h1b, row_ptr, csr, dinv, b1, aggb, N);

    // layer 2 transform (MFMA, split W2)
    k_gemm2_mfma<<<(N + 63) / 64, 256, 0, stream>>>(aggb, W2, h2b, N);

    // final gather + bias -> out (f32)
    k_gather<OUT_CH><<<gs((long long)N * (OUT_CH / 4)), 256, 0, stream>>>(
        h2b, row_ptr, csr, dinv, b2, out, N);
}